// Round 8
// baseline (158.840 us; speedup 1.0000x reference)
//
#include <hip/hip_runtime.h>
#include <math.h>

#define BB  2
#define SS  2048
#define DD  768
#define HH  12
#define HDD 64
#define BSR (BB * SS)   // 4096
#define NCH 40          // equal-work chunks per (b,h)  (QBLK=128)
#define NKT 12          // K-steps (768/64)

typedef __attribute__((ext_vector_type(8))) short bf16x8;   // 8 bf16 = 4 VGPRs
typedef __attribute__((ext_vector_type(4))) float f32x4;
typedef __attribute__((ext_vector_type(4))) int  i32x4;     // 16B copy unit

__device__ inline f32x4 mfma16(bf16x8 a, bf16x8 b, f32x4 c) {
    return __builtin_amdgcn_mfma_f32_16x16x32_bf16(a, b, c, 0, 0, 0);
}

// fp32 -> bf16 round-to-nearest-even (scalar, scattered-dest paths only)
__device__ inline unsigned short f2b(float f) {
    unsigned int u = __float_as_uint(f);
    u += 0x7FFFu + ((u >> 16) & 1u);
    return (unsigned short)(u >> 16);
}
__device__ inline float b2f(unsigned short u) {
    return __uint_as_float((unsigned int)u << 16);
}

// HW packed fp32x2 -> bf16x2 (RNE)
__device__ inline unsigned int cvt_pk_bf16(float lo, float hi) {
    unsigned int r;
    asm("v_cvt_pk_bf16_f32 %0, %1, %2" : "=v"(r) : "v"(lo), "v"(hi));
    return r;
}

// async global->LDS 16B copy (LDS dest = wave-uniform base + lane*16)
__device__ inline void async_copy16(void* lds, const void* g) {
    __builtin_amdgcn_global_load_lds(
        (const __attribute__((address_space(1))) unsigned int*)g,
        (__attribute__((address_space(3))) unsigned int*)lds, 16, 0, 0);
}

// ---------------------------------------------------------------------------
// x fp32 -> bf16 (once; removes the 3x fp32 re-read in qkv A-staging)
// ---------------------------------------------------------------------------
__global__ __launch_bounds__(256) void conv_x_kernel(
    const float* __restrict__ x, unsigned short* __restrict__ xb)
{
    const size_t i = ((size_t)blockIdx.x * 256 + threadIdx.x) * 8;
    float4 f0 = *(const float4*)&x[i];
    float4 f1 = *(const float4*)&x[i + 4];
    i32x4 tv;
    tv[0] = (int)cvt_pk_bf16(f0.x, f0.y);
    tv[1] = (int)cvt_pk_bf16(f0.z, f0.w);
    tv[2] = (int)cvt_pk_bf16(f1.x, f1.y);
    tv[3] = (int)cvt_pk_bf16(f1.z, f1.w);
    *(i32x4*)&xb[i] = tv;
}

// ---------------------------------------------------------------------------
// Weight transpose-convert: w[k][n] fp32 -> wT[n][k] bf16
// ---------------------------------------------------------------------------
__global__ __launch_bounds__(256) void conv_wT_kernel(
    const float* __restrict__ w0, const float* __restrict__ w1,
    const float* __restrict__ w2, const float* __restrict__ w3,
    unsigned short* __restrict__ o0, unsigned short* __restrict__ o1,
    unsigned short* __restrict__ o2, unsigned short* __restrict__ o3)
{
    const float* w = (blockIdx.z == 0) ? w0 : (blockIdx.z == 1) ? w1
                   : (blockIdx.z == 2) ? w2 : w3;
    unsigned short* o = (blockIdx.z == 0) ? o0 : (blockIdx.z == 1) ? o1
                      : (blockIdx.z == 2) ? o2 : o3;
    const int n0 = blockIdx.x * 64;
    const int k0 = blockIdx.y * 64;
    const int tid = threadIdx.x;

    __shared__ unsigned short tile[64][72];

#pragma unroll
    for (int p = 0; p < 4; ++p) {
        int c  = p * 256 + tid;
        int kr = c >> 4;
        int nc = (c & 15) * 4;
        float4 v = *(const float4*)&w[(size_t)(k0 + kr) * DD + n0 + nc];
        tile[nc + 0][kr] = f2b(v.x);
        tile[nc + 1][kr] = f2b(v.y);
        tile[nc + 2][kr] = f2b(v.z);
        tile[nc + 3][kr] = f2b(v.w);
    }
    __syncthreads();
#pragma unroll
    for (int p = 0; p < 2; ++p) {
        int c  = p * 256 + tid;
        int nr = c >> 3;
        int kc = (c & 7) * 8;
        *(i32x4*)&o[(size_t)(n0 + nr) * DD + k0 + kc] = *(const i32x4*)&tile[nr][kc];
    }
}

// ---------------------------------------------------------------------------
// QKV projection GEMM, 64x128 tile, double-buffered 2-phase, all-async
// staging (xb bf16).  1D grid with XCD swizzle: the 18 blocks sharing an
// m-tile (6 n x 3 which) land on ONE XCD -> A re-reads hit that XCD's L2.
// ---------------------------------------------------------------------------
__global__ __launch_bounds__(256) void qkv_gemm_kernel(
    const unsigned short* __restrict__ xb,
    const unsigned short* __restrict__ wqT, const unsigned short* __restrict__ wkT,
    const unsigned short* __restrict__ wvT,
    const float* __restrict__ bq, const float* __restrict__ bk,
    const float* __restrict__ bv,
    unsigned short* __restrict__ Qg, unsigned short* __restrict__ Kg,
    unsigned short* __restrict__ Vg)
{
    // XCD decode: p%8 = xcd (HW round-robin), slot = p/8 in [0,144)
    const int p0   = blockIdx.x;
    const int xcd  = p0 & 7;
    const int slot = p0 >> 3;
    const int m_t  = (slot / 18) * 8 + xcd;   // 0..63
    const int nw   = slot % 18;
    const int n_t  = nw / 3;                  // 0..5
    const int which = nw % 3;

    const unsigned short* Bt = (which == 0) ? wqT : (which == 1) ? wkT : wvT;
    const float* bias        = (which == 0) ? bq  : (which == 1) ? bk  : bv;
    unsigned short* out      = (which == 0) ? Qg  : (which == 1) ? Kg  : Vg;
    const float qs           = (which == 0) ? 0.18033688011112042f : 1.0f;

    const int m0 = m_t * 64;
    const int n0 = n_t * 128;
    const int tid  = threadIdx.x;
    const int w    = tid >> 6;
    const int lane = tid & 63;
    const int quad = lane >> 4;
    const int l16  = lane & 15;
    const int mh   = w & 1;
    const int nh   = w >> 1;
    const int swz  = l16 & 7;

    __shared__ unsigned short smem[24576];
    unsigned short (*As0)[64] = (unsigned short(*)[64])smem;
    unsigned short (*Bs0)[64] = (unsigned short(*)[64])(smem + 4096);
    unsigned short (*As1)[64] = (unsigned short(*)[64])(smem + 12288);
    unsigned short (*Bs1)[64] = (unsigned short(*)[64])(smem + 16384);
    unsigned short (*T)[136]  = (unsigned short(*)[136])smem;

    const unsigned short* gA[2];
    int ldsA[2];
#pragma unroll
    for (int p = 0; p < 2; ++p) {
        int c  = p * 256 + tid;
        int r  = c >> 3;
        int j  = c & 7;
        int ch = j ^ (r & 7);
        gA[p]   = &xb[(size_t)(m0 + r) * DD + ch * 8];
        ldsA[p] = r * 64 + j * 8;
    }
    const unsigned short* gB[4];
    int ldsB[4];
#pragma unroll
    for (int p = 0; p < 4; ++p) {
        int c  = p * 256 + tid;
        int r  = c >> 3;
        int j  = c & 7;
        int ch = j ^ (r & 7);
        gB[p]   = &Bt[(size_t)(n0 + r) * DD + ch * 8];
        ldsB[p] = r * 64 + j * 8;
    }

    f32x4 zero = {0.f, 0.f, 0.f, 0.f};
    f32x4 acc[2][4];
#pragma unroll
    for (int i = 0; i < 2; ++i)
#pragma unroll
        for (int j = 0; j < 4; ++j) acc[i][j] = zero;

#pragma unroll
    for (int p = 0; p < 2; ++p) async_copy16((unsigned short*)As0 + ldsA[p], gA[p]);
#pragma unroll
    for (int p = 0; p < 4; ++p) async_copy16((unsigned short*)Bs0 + ldsB[p], gB[p]);
    __syncthreads();

#pragma unroll
    for (int t = 0; t < NKT; ++t) {
        const int kn = (t + 1) * 64;
        unsigned short (*As)[64] = (t & 1) ? As1 : As0;
        unsigned short (*Bs)[64] = (t & 1) ? Bs1 : Bs0;
        unsigned short (*An)[64] = (t & 1) ? As0 : As1;
        unsigned short (*Bn)[64] = (t & 1) ? Bs0 : Bs1;
        if (t + 1 < NKT) {
#pragma unroll
            for (int p = 0; p < 2; ++p)
                async_copy16((unsigned short*)An + ldsA[p], gA[p] + kn);
#pragma unroll
            for (int p = 0; p < 4; ++p)
                async_copy16((unsigned short*)Bn + ldsB[p], gB[p] + kn);
        }
        bf16x8 af0[2], af1[2], bf0[4], bf1[4];
#pragma unroll
        for (int mt = 0; mt < 2; ++mt) {
            int r = mh * 32 + mt * 16 + l16;
            af0[mt] = *(const bf16x8*)&As[r][((quad    ) ^ swz) * 8];
            af1[mt] = *(const bf16x8*)&As[r][((quad + 4) ^ swz) * 8];
        }
#pragma unroll
        for (int nt = 0; nt < 4; ++nt) {
            int r = nh * 64 + nt * 16 + l16;
            bf0[nt] = *(const bf16x8*)&Bs[r][((quad    ) ^ swz) * 8];
            bf1[nt] = *(const bf16x8*)&Bs[r][((quad + 4) ^ swz) * 8];
        }
#pragma unroll
        for (int mt = 0; mt < 2; ++mt)
#pragma unroll
            for (int nt = 0; nt < 4; ++nt) {
                acc[mt][nt] = mfma16(af0[mt], bf0[nt], acc[mt][nt]);
                acc[mt][nt] = mfma16(af1[mt], bf1[nt], acc[mt][nt]);
            }
        __syncthreads();
    }

    if (which < 2) {
#pragma unroll
        for (int nt = 0; nt < 4; ++nt) {
            const int col = nh * 64 + nt * 16 + l16;
            const float bvv = bias[n0 + col];
#pragma unroll
            for (int mt = 0; mt < 2; ++mt)
#pragma unroll
                for (int r = 0; r < 4; ++r)
                    T[mh * 32 + mt * 16 + quad * 4 + r][col] =
                        f2b((acc[mt][nt][r] + bvv) * qs);
        }
        __syncthreads();
#pragma unroll
        for (int p2 = 0; p2 < 4; ++p2) {
            int c    = p2 * 256 + tid;
            int row  = c >> 4;
            int ck   = c & 15;
            int head = ck >> 3;
            int wi   = ck & 7;
            int sg   = m0 + row;
            int bi   = sg >> 11, si = sg & 2047;
            int hcol = (n0 >> 6) + head;
            *(i32x4*)&out[(((size_t)(bi * HH + hcol)) * SS + si) * HDD + wi * 8] =
                *(const i32x4*)&T[row][head * 64 + wi * 8];
        }
    } else {
        for (int pass = 0; pass < 2; ++pass) {
            if (pass) __syncthreads();
            if (nh == pass) {
#pragma unroll
                for (int nt = 0; nt < 4; ++nt) {
                    const float bvv = bias[n0 + pass * 64 + nt * 16 + l16];
#pragma unroll
                    for (int mt = 0; mt < 2; ++mt) {
                        uint2 pk;
                        pk.x = cvt_pk_bf16(acc[mt][nt][0] + bvv, acc[mt][nt][1] + bvv);
                        pk.y = cvt_pk_bf16(acc[mt][nt][2] + bvv, acc[mt][nt][3] + bvv);
                        *(uint2*)&T[nt * 16 + l16][mh * 32 + mt * 16 + quad * 4] = pk;
                    }
                }
            }
            __syncthreads();
            const int bi   = m0 >> 11;
            const int s0   = m0 & 2047;
            const int hcol = (n0 >> 6) + pass;
#pragma unroll
            for (int p2 = 0; p2 < 2; ++p2) {
                int c    = p2 * 256 + tid;
                int drow = c >> 3;
                int wi   = c & 7;
                *(i32x4*)&out[(((size_t)(bi * HH + hcol)) * HDD + drow) * SS + s0 + wi * 8] =
                    *(const i32x4*)&T[drow][wi * 8];
            }
        }
    }
}

// ---------------------------------------------------------------------------
// Output projection GEMM with FUSED MERGE: K-step t == head t, so A-staging
// loads the <=4 Opart chunk partials + Lb sums for head t, merges in fp32
// regs (sum, x 1/suml, cvt_pk) and ds_writes the bf16 A-tile (XOR-swizzled
// chunks).  Deletes the merge kernel + cb round-trip.  B async as before.
// ---------------------------------------------------------------------------
__global__ __launch_bounds__(256) void out_gemm_kernel(
    const unsigned short* __restrict__ Opart, const float* __restrict__ Lb,
    const unsigned short* __restrict__ woT,
    const float* __restrict__ bo, float* __restrict__ out)
{
    const int p0   = blockIdx.x;          // 0..383
    const int xcd  = p0 & 7;
    const int slot = p0 >> 3;             // 0..47
    const int m0 = ((slot / 6) * 8 + xcd) * 64;
    const int n0 = (slot % 6) * 128;
    const int tid  = threadIdx.x;
    const int w    = tid >> 6;
    const int lane = tid & 63;
    const int quad = lane >> 4;
    const int l16  = lane & 15;
    const int mh   = w & 1;
    const int nh   = w >> 1;
    const int swz  = l16 & 7;

    // merge geometry for this m-tile (64 rows = one half of one 128-q tile)
    const int bi   = m0 >> 11;
    const int s0   = m0 & 2047;
    const int qt2  = s0 >> 7;
    const int half = (s0 >> 6) & 1;
    const int nch = (qt2 < 4) ? 1 : (qt2 < 8) ? 2 : (qt2 < 12) ? 3 : 4;
    const int cb0 = (qt2 < 4) ? qt2
                  : (qt2 < 8)  ? (4  + (qt2 - 4)  * 2)
                  : (qt2 < 12) ? (12 + (qt2 - 8)  * 3)
                  :              (24 + (qt2 - 12) * 4);

    __shared__ unsigned short smem[24576];
    unsigned short (*As0)[64] = (unsigned short(*)[64])smem;
    unsigned short (*Bs0)[64] = (unsigned short(*)[64])(smem + 4096);
    unsigned short (*As1)[64] = (unsigned short(*)[64])(smem + 12288);
    unsigned short (*Bs1)[64] = (unsigned short(*)[64])(smem + 16384);

    // A-merge thread coords: one row, 16 contiguous d per thread
    const int arow = tid >> 2;            // 0..63
    const int ad0  = (tid & 3) * 16;      // 0,16,32,48
    const int aj0  = ad0 >> 3;            // first of two 8-col chunks
    const int aw0  = arow * 64 + ((aj0      ^ (arow & 7)) * 8);
    const int aw1  = arow * 64 + (((aj0 + 1) ^ (arow & 7)) * 8);
    // Opart row index for (ci, t): rbase[ci] + t*rstep
    const size_t rstep = (size_t)NCH * 128;
    size_t rbase[4];
#pragma unroll
    for (int ci = 0; ci < 4; ++ci)
        rbase[ci] = ((size_t)(bi * HH) * NCH + cb0 + ci) * 128 + half * 64 + arow;

    const unsigned short* gB[4];
    int ldsB[4];
#pragma unroll
    for (int p = 0; p < 4; ++p) {
        int c  = p * 256 + tid;
        int r  = c >> 3;
        int j  = c & 7;
        int ch = j ^ (r & 7);
        gB[p]   = &woT[(size_t)(n0 + r) * DD + ch * 8];
        ldsB[p] = r * 64 + j * 8;
    }

    f32x4 zero = {0.f, 0.f, 0.f, 0.f};
    f32x4 acc[2][4];
#pragma unroll
    for (int i = 0; i < 2; ++i)
#pragma unroll
        for (int j = 0; j < 4; ++j) acc[i][j] = zero;

    // merge-load regs for the staged K-step
    i32x4 pa[4][2];
    float pl[4];

    // ---- prologue: stage K-step 0 ----
#pragma unroll
    for (int ci = 0; ci < 4; ++ci) if (ci < nch) {
        const unsigned short* o = Opart + rbase[ci] * HDD + ad0;
        pa[ci][0] = *(const i32x4*)&o[0];
        pa[ci][1] = *(const i32x4*)&o[8];
        pl[ci] = Lb[rbase[ci]];
    }
#pragma unroll
    for (int p = 0; p < 4; ++p) async_copy16((unsigned short*)Bs0 + ldsB[p], gB[p]);
    {
        float suml = 0.f, a16[16];
#pragma unroll
        for (int i = 0; i < 16; ++i) a16[i] = 0.f;
#pragma unroll
        for (int ci = 0; ci < 4; ++ci) if (ci < nch) {
            suml += pl[ci];
#pragma unroll
            for (int wd = 0; wd < 4; ++wd) {
                unsigned int ua = (unsigned int)pa[ci][0][wd];
                a16[wd * 2 + 0] += __uint_as_float(ua << 16);
                a16[wd * 2 + 1] += __uint_as_float(ua & 0xffff0000u);
                unsigned int ub = (unsigned int)pa[ci][1][wd];
                a16[8 + wd * 2 + 0] += __uint_as_float(ub << 16);
                a16[8 + wd * 2 + 1] += __uint_as_float(ub & 0xffff0000u);
            }
        }
        const float inv = 1.0f / suml;
        unsigned int res[8];
#pragma unroll
        for (int i = 0; i < 8; ++i)
            res[i] = cvt_pk_bf16(a16[2 * i] * inv, a16[2 * i + 1] * inv);
        *(i32x4*)((unsigned short*)As0 + aw0) = *(const i32x4*)&res[0];
        *(i32x4*)((unsigned short*)As0 + aw1) = *(const i32x4*)&res[4];
    }
    __syncthreads();

#pragma unroll
    for (int t = 0; t < NKT; ++t) {
        const int kn = (t + 1) * 64;
        unsigned short (*As)[64] = (t & 1) ? As1 : As0;
        unsigned short (*Bs)[64] = (t & 1) ? Bs1 : Bs0;
        unsigned short (*An)[64] = (t & 1) ? As0 : As1;
        unsigned short (*Bn)[64] = (t & 1) ? Bs0 : Bs1;
        const bool more = (t + 1 < NKT);

        if (more) {
            // issue next-head loads BEFORE compute (latency hides under MFMA)
#pragma unroll
            for (int ci = 0; ci < 4; ++ci) if (ci < nch) {
                const size_t rr = rbase[ci] + (size_t)(t + 1) * rstep;
                const unsigned short* o = Opart + rr * HDD + ad0;
                pa[ci][0] = *(const i32x4*)&o[0];
                pa[ci][1] = *(const i32x4*)&o[8];
                pl[ci] = Lb[rr];
            }
#pragma unroll
            for (int p = 0; p < 4; ++p)
                async_copy16((unsigned short*)Bn + ldsB[p], gB[p] + kn);
        }

        bf16x8 af0[2], af1[2], bf0[4], bf1[4];
#pragma unroll
        for (int mt = 0; mt < 2; ++mt) {
            int r = mh * 32 + mt * 16 + l16;
            af0[mt] = *(const bf16x8*)&As[r][((quad    ) ^ swz) * 8];
            af1[mt] = *(const bf16x8*)&As[r][((quad + 4) ^ swz) * 8];
        }
#pragma unroll
        for (int nt = 0; nt < 4; ++nt) {
            int r = nh * 64 + nt * 16 + l16;
            bf0[nt] = *(const bf16x8*)&Bs[r][((quad    ) ^ swz) * 8];
            bf1[nt] = *(const bf16x8*)&Bs[r][((quad + 4) ^ swz) * 8];
        }
#pragma unroll
        for (int mt = 0; mt < 2; ++mt)
#pragma unroll
            for (int nt = 0; nt < 4; ++nt) {
                acc[mt][nt] = mfma16(af0[mt], bf0[nt], acc[mt][nt]);
                acc[mt][nt] = mfma16(af1[mt], bf1[nt], acc[mt][nt]);
            }

        if (more) {
            // merge + convert + write next A-tile
            float suml = 0.f, a16[16];
#pragma unroll
            for (int i = 0; i < 16; ++i) a16[i] = 0.f;
#pragma unroll
            for (int ci = 0; ci < 4; ++ci) if (ci < nch) {
                suml += pl[ci];
#pragma unroll
                for (int wd = 0; wd < 4; ++wd) {
                    unsigned int ua = (unsigned int)pa[ci][0][wd];
                    a16[wd * 2 + 0] += __uint_as_float(ua << 16);
                    a16[wd * 2 + 1] += __uint_as_float(ua & 0xffff0000u);
                    unsigned int ub = (unsigned int)pa[ci][1][wd];
                    a16[8 + wd * 2 + 0] += __uint_as_float(ub << 16);
                    a16[8 + wd * 2 + 1] += __uint_as_float(ub & 0xffff0000u);
                }
            }
            const float inv = 1.0f / suml;
            unsigned int res[8];
#pragma unroll
            for (int i = 0; i < 8; ++i)
                res[i] = cvt_pk_bf16(a16[2 * i] * inv, a16[2 * i + 1] * inv);
            *(i32x4*)((unsigned short*)An + aw0) = *(const i32x4*)&res[0];
            *(i32x4*)((unsigned short*)An + aw1) = *(const i32x4*)&res[4];
        }
        __syncthreads();
    }

#pragma unroll
    for (int nt = 0; nt < 4; ++nt) {
        const int n = n0 + nh * 64 + nt * 16 + l16;
        const float bvv = bo[n];
#pragma unroll
        for (int mt = 0; mt < 2; ++mt) {
            const int mbase = m0 + mh * 32 + mt * 16 + quad * 4;
#pragma unroll
            for (int r = 0; r < 4; ++r)
                out[(size_t)(mbase + r) * DD + n] = acc[mt][nt][r] + bvv;
        }
    }
}

// ---------------------------------------------------------------------------
// MFMA flash attention, QBLK=128, XCD swizzle (R5 structure: single-buffer
// K/V LDS, 34 KB, 4 blocks/CU — R6's dbuf traded occupancy and regressed).
// ---------------------------------------------------------------------------
__global__ __launch_bounds__(256, 4) void attn_mfma_kernel(
    const unsigned short* __restrict__ Qg, const unsigned short* __restrict__ Kg,
    const unsigned short* __restrict__ Vg, unsigned short* __restrict__ Opart,
    float* __restrict__ Lb)
{
    // XCD decode: 960 blocks; xcd = p%8, 3 bh-groups x 40 chunks per XCD
    const int p0   = blockIdx.x;
    const int xcd  = p0 & 7;
    const int slot = p0 >> 3;               // 0..119
    const int bh_i = (slot / 40) * 8 + xcd; // 0..23
    const int c    = (NCH - 1) - (slot % 40);   // big-qt chunks dispatch first

    int qt, ck, nch;
    if (c < 4)       { qt = c;                            ck = 0;     nch = 1; }
    else if (c < 12) { int t = c - 4;  qt = 4  + (t >> 1); ck = t & 1; nch = 2; }
    else if (c < 24) { int t = c - 12; qt = 8  + t / 3;    ck = t % 3; nch = 3; }
    else             { int t = c - 24; qt = 12 + (t >> 2); ck = t & 3; nch = 4; }
    const int NT   = 2 * qt + 2;
    const int base = NT / nch, rem = NT % nch;
    const int lo   = ck * base + min(ck, rem);
    const int hi   = lo + base + (ck < rem ? 1 : 0);
    const int dlo  = 2 * qt;

    const int tid  = threadIdx.x;
    const int w    = tid >> 6;
    const int lane = tid & 63;
    const int quad = lane >> 4;
    const int l16  = lane & 15;
    const int q0   = qt * 128;

    const size_t bh = (size_t)bh_i;
    const unsigned short* qp = Qg + bh * SS * HDD;
    const unsigned short* kp = Kg + bh * SS * HDD;
    const unsigned short* vp = Vg + bh * HDD * SS;   // [d][s]

    unsigned short* op = Opart + ((size_t)bh * NCH + c) * 128 * HDD;
    float* lp = Lb + ((size_t)bh * NCH + c) * 128;

    __shared__ unsigned short Ks[64][64];        // [key][d], XOR-swizzled chunks
    __shared__ unsigned short Vt[64][64];        // [d][key], XOR-swizzled chunks
    __shared__ unsigned short PsT[4][2][16][72]; // per-wave [qf][query(l16)][key]
    unsigned short* slab = &PsT[w][0][0][0];

    bf16x8 qb0[2], qb1[2];
    int query[2];
#pragma unroll
    for (int qf = 0; qf < 2; ++qf) {
        query[qf] = q0 + w * 32 + qf * 16 + l16;
        qb0[qf] = *(const bf16x8*)&qp[(size_t)query[qf] * HDD + quad * 8];
        qb1[qf] = *(const bf16x8*)&qp[(size_t)query[qf] * HDD + 32 + quad * 8];
    }

    const int pr  = tid >> 3;          // 0..31
    const int po8 = tid & 7;
    const int fs  = l16 & 7;

    i32x4 kpre[2], vpre[2];
#pragma unroll
    for (int p = 0; p < 2; ++p) {
        int r  = pr + p * 32;
        int gc = (po8 ^ (r & 7)) * 8;
        kpre[p] = *(const i32x4*)&kp[(size_t)(lo * 64 + r) * HDD + gc];
        vpre[p] = *(const i32x4*)&vp[(size_t)r * SS + lo * 64 + gc];
    }

    f32x4 zero = {0.f, 0.f, 0.f, 0.f};
    f32x4 o_acc[2][4];
    float l_i[2] = {0.f, 0.f};
#pragma unroll
    for (int qf = 0; qf < 2; ++qf)
#pragma unroll
        for (int i = 0; i < 4; ++i) o_acc[qf][i] = zero;

    for (int kt = lo; kt < hi; ++kt) {
        const int k0 = kt * 64;
        __syncthreads();
#pragma unroll
        for (int p = 0; p < 2; ++p) {
            int r = pr + p * 32;
            *(i32x4*)&Ks[r][po8 * 8] = kpre[p];
            *(i32x4*)&Vt[r][po8 * 8] = vpre[p];
        }
        __syncthreads();

        if (kt + 1 < hi) {
            const int kn = (kt + 1) * 64;
#pragma unroll
            for (int p = 0; p < 2; ++p) {
                int r  = pr + p * 32;
                int gc = (po8 ^ (r & 7)) * 8;
                kpre[p] = *(const i32x4*)&kp[(size_t)(kn + r) * HDD + gc];
                vpre[p] = *(const i32x4*)&vp[(size_t)r * SS + kn + gc];
            }
        }

        // ---- S^T = K·Q^T, softmax, P^T staging ----
        const bool diag = (kt >= dlo);
#pragma unroll
        for (int t = 0; t < 4; ++t) {
            const int row = t * 16 + l16;
            bf16x8 klo = *(const bf16x8*)&Ks[row][((quad    ) ^ fs) * 8];
            bf16x8 khi = *(const bf16x8*)&Ks[row][((quad + 4) ^ fs) * 8];
#pragma unroll
            for (int qf = 0; qf < 2; ++qf) {
                f32x4 s = mfma16(klo, qb0[qf], zero);
                s = mfma16(khi, qb1[qf], s);
                float pv[4];
#pragma unroll
                for (int r = 0; r < 4; ++r) {
                    const int key = k0 + t * 16 + quad * 4 + r;
                    float p = exp2f(s[r]);
                    if (diag && key > query[qf]) p = 0.f;
                    pv[r] = p;
                    l_i[qf] += p;
                }
                uint2 pk;
                pk.x = cvt_pk_bf16(pv[0], pv[1]);
                pk.y = cvt_pk_bf16(pv[2], pv[3]);
                *(uint2*)&slab[(qf * 16 + l16) * 72 + t * 16 + quad * 4] = pk;
            }
        }

        // ---- O^T += V^T · P^T ----
        bf16x8 pb0[2], pb1[2];
#pragma unroll
        for (int qf = 0; qf < 2; ++qf) {
            pb0[qf] = *(const bf16x8*)&slab[(qf * 16 + l16) * 72 + quad * 8];
            pb1[qf] = *(const bf16x8*)&slab[(qf * 16 + l16) * 72 + 32 + quad * 8];
        }
#pragma unroll
        for (int t2 = 0; t2 < 4; ++t2) {
            const int row = t2 * 16 + l16;
            bf16x8 vlo = *(const bf16x8*)&Vt[row][((quad    ) ^ fs) * 8];
            bf16x8 vhi = *(const bf16x8*)&Vt[row][((quad + 4) ^ fs) * 8];
#pragma unroll
            for (int qf = 0; qf < 2; ++qf) {
                o_acc[qf][t2] = mfma16(vlo, pb0[qf], o_acc[qf][t2]);
                o_acc[qf][t2] = mfma16(vhi, pb1[qf], o_acc[qf][t2]);
            }
        }
    }

    // ---- epilogue ----
#pragma unroll
    for (int qf = 0; qf < 2; ++qf) {
        float l = l_i[qf];
        l += __shfl_xor(l, 16);
        l += __shfl_xor(l, 32);
        if (quad == 0) lp[w * 32 + qf * 16 + l16] = l;
#pragma unroll
        for (int t2 = 0; t2 < 4; ++t2) {
            uint2 pk;
            pk.x = cvt_pk_bf16(o_acc[qf][t2][0], o_acc[qf][t2][1]);
            pk.y = cvt_pk_bf16(o_acc[qf][t2][2], o_acc[qf][t2][3]);
            *(uint2*)&slab[(qf * 16 + l16) * 72 + t2 * 16 + quad * 4] = pk;
        }
    }
#pragma unroll
    for (int p2 = 0; p2 < 4; ++p2) {
        int cc  = p2 * 64 + lane;
        int row = cc >> 3, dc = cc & 7;
        *(i32x4*)&op[(size_t)(w * 32 + row) * HDD + dc * 8] =
            *(const i32x4*)&slab[row * 72 + dc * 8];
    }
}

// ---------------------------------------------------------------------------
extern "C" void kernel_launch(void* const* d_in, const int* in_sizes, int n_in,
                              void* d_out, int out_size, void* d_ws, size_t ws_size,
                              hipStream_t stream)
{
    const float* x  = (const float*)d_in[0];
    const float* wq = (const float*)d_in[1];
    const float* bq = (const float*)d_in[2];
    const float* wk = (const float*)d_in[3];
    const float* bk = (const float*)d_in[4];
    const float* wv = (const float*)d_in[5];
    const float* bv = (const float*)d_in[6];
    const float* wo = (const float*)d_in[7];
    const float* bo = (const float*)d_in[8];
    float* out = (float*)d_out;

    char* p = (char*)d_ws;
    const size_t XB  = (size_t)BSR * DD * 2;
    const size_t WB  = (size_t)DD * DD * 2;
    const size_t OPB = (size_t)BB * HH * NCH * 128 * HDD * 2;
    const size_t LBB = (size_t)BB * HH * NCH * 128 * 4;
    unsigned short* wqT = (unsigned short*)p;            p += WB;
    unsigned short* wkT = (unsigned short*)p;            p += WB;
    unsigned short* wvT = (unsigned short*)p;            p += WB;
    unsigned short* woT = (unsigned short*)p;            p += WB;
    unsigned short* xb  = (unsigned short*)p;            p += XB;
    unsigned short* Qg  = (unsigned short*)p;            p += XB;
    unsigned short* Kg  = (unsigned short*)p;            p += XB;
    unsigned short* Vg  = (unsigned short*)p;            p += XB;
    unsigned short* Opart = (unsigned short*)p;          p += OPB;
    float* Lb = (float*)p;                               p += LBB;

    conv_x_kernel<<<dim3(BSR * DD / (256 * 8)), 256, 0, stream>>>(x, xb);
    conv_wT_kernel<<<dim3(DD / 64, DD / 64, 4), 256, 0, stream>>>(
        wq, wk, wv, wo, wqT, wkT, wvT, woT);
    qkv_gemm_kernel<<<dim3(1152), 256, 0, stream>>>(
        xb, wqT, wkT, wvT, bq, bk, bv, Qg, Kg, Vg);
    attn_mfma_kernel<<<dim3(960), 256, 0, stream>>>(
        Qg, Kg, Vg, Opart, Lb);
    out_gemm_kernel<<<dim3(384), 256, 0, stream>>>(Opart, Lb, woT, bo, out);
}

// Round 10
// 150.576 us; speedup vs baseline: 1.0549x; 1.0549x over previous
//
#include <hip/hip_runtime.h>
#include <math.h>

#define BB  2
#define SS  2048
#define DD  768
#define HH  12
#define HDD 64
#define BSR (BB * SS)   // 4096
#define NCH 40          // equal-work chunks per (b,h)  (QBLK=128)
#define NKT 12          // K-steps (768/64)
#define NXB 1536        // x-conversion blocks: BSR*DD/(256*8)

typedef __attribute__((ext_vector_type(8))) short bf16x8;   // 8 bf16 = 4 VGPRs
typedef __attribute__((ext_vector_type(4))) float f32x4;
typedef __attribute__((ext_vector_type(4))) int  i32x4;     // 16B copy unit

__device__ inline f32x4 mfma16(bf16x8 a, bf16x8 b, f32x4 c) {
    return __builtin_amdgcn_mfma_f32_16x16x32_bf16(a, b, c, 0, 0, 0);
}

// fp32 -> bf16 round-to-nearest-even (scalar, scattered-dest paths only)
__device__ inline unsigned short f2b(float f) {
    unsigned int u = __float_as_uint(f);
    u += 0x7FFFu + ((u >> 16) & 1u);
    return (unsigned short)(u >> 16);
}
__device__ inline float b2f(unsigned short u) {
    return __uint_as_float((unsigned int)u << 16);
}

// HW packed fp32x2 -> bf16x2 (RNE)
__device__ inline unsigned int cvt_pk_bf16(float lo, float hi) {
    unsigned int r;
    asm("v_cvt_pk_bf16_f32 %0, %1, %2" : "=v"(r) : "v"(lo), "v"(hi));
    return r;
}

// async global->LDS 16B copy (LDS dest = wave-uniform base + lane*16)
__device__ inline void async_copy16(void* lds, const void* g) {
    __builtin_amdgcn_global_load_lds(
        (const __attribute__((address_space(1))) unsigned int*)g,
        (__attribute__((address_space(3))) unsigned int*)lds, 16, 0, 0);
}

// ---------------------------------------------------------------------------
// Combined input conversion (one launch instead of two):
//   blocks 0..1535    : x fp32 -> bf16 (flat, 8 elems/thread, 2048/block)
//   blocks 1536..2111 : w[k][n] fp32 -> wT[n][k] bf16 (4 weights, 144 tiles ea)
// ---------------------------------------------------------------------------
__global__ __launch_bounds__(256) void conv_all_kernel(
    const float* __restrict__ x,
    const float* __restrict__ w0, const float* __restrict__ w1,
    const float* __restrict__ w2, const float* __restrict__ w3,
    unsigned short* __restrict__ xb,
    unsigned short* __restrict__ o0, unsigned short* __restrict__ o1,
    unsigned short* __restrict__ o2, unsigned short* __restrict__ o3)
{
    const int blk = blockIdx.x;
    const int tid = threadIdx.x;

    __shared__ unsigned short tile[64][72];

    if (blk < NXB) {
        // ---- x conversion ----
        const size_t i = ((size_t)blk * 256 + tid) * 8;
        float4 f0 = *(const float4*)&x[i];
        float4 f1 = *(const float4*)&x[i + 4];
        i32x4 tv;
        tv[0] = (int)cvt_pk_bf16(f0.x, f0.y);
        tv[1] = (int)cvt_pk_bf16(f0.z, f0.w);
        tv[2] = (int)cvt_pk_bf16(f1.x, f1.y);
        tv[3] = (int)cvt_pk_bf16(f1.z, f1.w);
        *(i32x4*)&xb[i] = tv;
    } else {
        // ---- weight transpose-convert ----
        const int b2  = blk - NXB;          // 0..575
        const int z   = b2 / 144;           // which weight
        const int idx = b2 % 144;
        const int n0  = (idx % 12) * 64;
        const int k0  = (idx / 12) * 64;
        const float* w = (z == 0) ? w0 : (z == 1) ? w1 : (z == 2) ? w2 : w3;
        unsigned short* o = (z == 0) ? o0 : (z == 1) ? o1 : (z == 2) ? o2 : o3;

#pragma unroll
        for (int p = 0; p < 4; ++p) {
            int c  = p * 256 + tid;
            int kr = c >> 4;
            int nc = (c & 15) * 4;
            float4 v = *(const float4*)&w[(size_t)(k0 + kr) * DD + n0 + nc];
            tile[nc + 0][kr] = f2b(v.x);
            tile[nc + 1][kr] = f2b(v.y);
            tile[nc + 2][kr] = f2b(v.z);
            tile[nc + 3][kr] = f2b(v.w);
        }
        __syncthreads();
#pragma unroll
        for (int p = 0; p < 2; ++p) {
            int c  = p * 256 + tid;
            int nr = c >> 3;
            int kc = (c & 7) * 8;
            *(i32x4*)&o[(size_t)(n0 + nr) * DD + k0 + kc] = *(const i32x4*)&tile[nr][kc];
        }
    }
}

// ---------------------------------------------------------------------------
// QKV projection GEMM, 64x128 tile, double-buffered 2-phase, all-async
// staging (xb bf16).  1D grid with XCD swizzle: the 18 blocks sharing an
// m-tile (6 n x 3 which) land on ONE XCD -> A re-reads hit that XCD's L2.
// ---------------------------------------------------------------------------
__global__ __launch_bounds__(256) void qkv_gemm_kernel(
    const unsigned short* __restrict__ xb,
    const unsigned short* __restrict__ wqT, const unsigned short* __restrict__ wkT,
    const unsigned short* __restrict__ wvT,
    const float* __restrict__ bq, const float* __restrict__ bk,
    const float* __restrict__ bv,
    unsigned short* __restrict__ Qg, unsigned short* __restrict__ Kg,
    unsigned short* __restrict__ Vg)
{
    // XCD decode: p%8 = xcd (HW round-robin), slot = p/8 in [0,144)
    const int p0   = blockIdx.x;
    const int xcd  = p0 & 7;
    const int slot = p0 >> 3;
    const int m_t  = (slot / 18) * 8 + xcd;   // 0..63
    const int nw   = slot % 18;
    const int n_t  = nw / 3;                  // 0..5
    const int which = nw % 3;

    const unsigned short* Bt = (which == 0) ? wqT : (which == 1) ? wkT : wvT;
    const float* bias        = (which == 0) ? bq  : (which == 1) ? bk  : bv;
    unsigned short* out      = (which == 0) ? Qg  : (which == 1) ? Kg  : Vg;
    const float qs           = (which == 0) ? 0.18033688011112042f : 1.0f;

    const int m0 = m_t * 64;
    const int n0 = n_t * 128;
    const int tid  = threadIdx.x;
    const int w    = tid >> 6;
    const int lane = tid & 63;
    const int quad = lane >> 4;
    const int l16  = lane & 15;
    const int mh   = w & 1;
    const int nh   = w >> 1;
    const int swz  = l16 & 7;

    __shared__ unsigned short smem[24576];
    unsigned short (*As0)[64] = (unsigned short(*)[64])smem;
    unsigned short (*Bs0)[64] = (unsigned short(*)[64])(smem + 4096);
    unsigned short (*As1)[64] = (unsigned short(*)[64])(smem + 12288);
    unsigned short (*Bs1)[64] = (unsigned short(*)[64])(smem + 16384);
    unsigned short (*T)[136]  = (unsigned short(*)[136])smem;

    const unsigned short* gA[2];
    int ldsA[2];
#pragma unroll
    for (int p = 0; p < 2; ++p) {
        int c  = p * 256 + tid;
        int r  = c >> 3;
        int j  = c & 7;
        int ch = j ^ (r & 7);
        gA[p]   = &xb[(size_t)(m0 + r) * DD + ch * 8];
        ldsA[p] = r * 64 + j * 8;
    }
    const unsigned short* gB[4];
    int ldsB[4];
#pragma unroll
    for (int p = 0; p < 4; ++p) {
        int c  = p * 256 + tid;
        int r  = c >> 3;
        int j  = c & 7;
        int ch = j ^ (r & 7);
        gB[p]   = &Bt[(size_t)(n0 + r) * DD + ch * 8];
        ldsB[p] = r * 64 + j * 8;
    }

    f32x4 zero = {0.f, 0.f, 0.f, 0.f};
    f32x4 acc[2][4];
#pragma unroll
    for (int i = 0; i < 2; ++i)
#pragma unroll
        for (int j = 0; j < 4; ++j) acc[i][j] = zero;

#pragma unroll
    for (int p = 0; p < 2; ++p) async_copy16((unsigned short*)As0 + ldsA[p], gA[p]);
#pragma unroll
    for (int p = 0; p < 4; ++p) async_copy16((unsigned short*)Bs0 + ldsB[p], gB[p]);
    __syncthreads();

#pragma unroll
    for (int t = 0; t < NKT; ++t) {
        const int kn = (t + 1) * 64;
        unsigned short (*As)[64] = (t & 1) ? As1 : As0;
        unsigned short (*Bs)[64] = (t & 1) ? Bs1 : Bs0;
        unsigned short (*An)[64] = (t & 1) ? As0 : As1;
        unsigned short (*Bn)[64] = (t & 1) ? Bs0 : Bs1;
        if (t + 1 < NKT) {
#pragma unroll
            for (int p = 0; p < 2; ++p)
                async_copy16((unsigned short*)An + ldsA[p], gA[p] + kn);
#pragma unroll
            for (int p = 0; p < 4; ++p)
                async_copy16((unsigned short*)Bn + ldsB[p], gB[p] + kn);
        }
        bf16x8 af0[2], af1[2], bf0[4], bf1[4];
#pragma unroll
        for (int mt = 0; mt < 2; ++mt) {
            int r = mh * 32 + mt * 16 + l16;
            af0[mt] = *(const bf16x8*)&As[r][((quad    ) ^ swz) * 8];
            af1[mt] = *(const bf16x8*)&As[r][((quad + 4) ^ swz) * 8];
        }
#pragma unroll
        for (int nt = 0; nt < 4; ++nt) {
            int r = nh * 64 + nt * 16 + l16;
            bf0[nt] = *(const bf16x8*)&Bs[r][((quad    ) ^ swz) * 8];
            bf1[nt] = *(const bf16x8*)&Bs[r][((quad + 4) ^ swz) * 8];
        }
#pragma unroll
        for (int mt = 0; mt < 2; ++mt)
#pragma unroll
            for (int nt = 0; nt < 4; ++nt) {
                acc[mt][nt] = mfma16(af0[mt], bf0[nt], acc[mt][nt]);
                acc[mt][nt] = mfma16(af1[mt], bf1[nt], acc[mt][nt]);
            }
        __syncthreads();
    }

    if (which < 2) {
#pragma unroll
        for (int nt = 0; nt < 4; ++nt) {
            const int col = nh * 64 + nt * 16 + l16;
            const float bvv = bias[n0 + col];
#pragma unroll
            for (int mt = 0; mt < 2; ++mt)
#pragma unroll
                for (int r = 0; r < 4; ++r)
                    T[mh * 32 + mt * 16 + quad * 4 + r][col] =
                        f2b((acc[mt][nt][r] + bvv) * qs);
        }
        __syncthreads();
#pragma unroll
        for (int p2 = 0; p2 < 4; ++p2) {
            int c    = p2 * 256 + tid;
            int row  = c >> 4;
            int ck   = c & 15;
            int head = ck >> 3;
            int wi   = ck & 7;
            int sg   = m0 + row;
            int bi   = sg >> 11, si = sg & 2047;
            int hcol = (n0 >> 6) + head;
            *(i32x4*)&out[(((size_t)(bi * HH + hcol)) * SS + si) * HDD + wi * 8] =
                *(const i32x4*)&T[row][head * 64 + wi * 8];
        }
    } else {
        for (int pass = 0; pass < 2; ++pass) {
            if (pass) __syncthreads();
            if (nh == pass) {
#pragma unroll
                for (int nt = 0; nt < 4; ++nt) {
                    const float bvv = bias[n0 + pass * 64 + nt * 16 + l16];
#pragma unroll
                    for (int mt = 0; mt < 2; ++mt) {
                        uint2 pk;
                        pk.x = cvt_pk_bf16(acc[mt][nt][0] + bvv, acc[mt][nt][1] + bvv);
                        pk.y = cvt_pk_bf16(acc[mt][nt][2] + bvv, acc[mt][nt][3] + bvv);
                        *(uint2*)&T[nt * 16 + l16][mh * 32 + mt * 16 + quad * 4] = pk;
                    }
                }
            }
            __syncthreads();
            const int bi   = m0 >> 11;
            const int s0   = m0 & 2047;
            const int hcol = (n0 >> 6) + pass;
#pragma unroll
            for (int p2 = 0; p2 < 2; ++p2) {
                int c    = p2 * 256 + tid;
                int drow = c >> 3;
                int wi   = c & 7;
                *(i32x4*)&out[(((size_t)(bi * HH + hcol)) * HDD + drow) * SS + s0 + wi * 8] =
                    *(const i32x4*)&T[drow][wi * 8];
            }
        }
    }
}

// ---------------------------------------------------------------------------
// Output projection GEMM: 64x128 tile, dbuf 2-phase, XCD swizzle (m-grouped).
// ---------------------------------------------------------------------------
__global__ __launch_bounds__(256) void out_gemm_kernel(
    const unsigned short* __restrict__ cb, const unsigned short* __restrict__ woT,
    const float* __restrict__ bo, float* __restrict__ out)
{
    const int p0   = blockIdx.x;          // 0..383
    const int xcd  = p0 & 7;
    const int slot = p0 >> 3;             // 0..47
    const int m0 = ((slot / 6) * 8 + xcd) * 64;
    const int n0 = (slot % 6) * 128;
    const int tid  = threadIdx.x;
    const int w    = tid >> 6;
    const int lane = tid & 63;
    const int quad = lane >> 4;
    const int l16  = lane & 15;
    const int mh   = w & 1;
    const int nh   = w >> 1;
    const int swz  = l16 & 7;

    __shared__ unsigned short smem[24576];
    unsigned short (*As0)[64] = (unsigned short(*)[64])smem;
    unsigned short (*Bs0)[64] = (unsigned short(*)[64])(smem + 4096);
    unsigned short (*As1)[64] = (unsigned short(*)[64])(smem + 12288);
    unsigned short (*Bs1)[64] = (unsigned short(*)[64])(smem + 16384);

    const unsigned short* gA[2];
    int ldsA[2];
#pragma unroll
    for (int p = 0; p < 2; ++p) {
        int c  = p * 256 + tid;
        int r  = c >> 3;
        int j  = c & 7;
        int ch = j ^ (r & 7);
        gA[p]   = &cb[(size_t)(m0 + r) * DD + ch * 8];
        ldsA[p] = r * 64 + j * 8;
    }
    const unsigned short* gB[4];
    int ldsB[4];
#pragma unroll
    for (int p = 0; p < 4; ++p) {
        int c  = p * 256 + tid;
        int r  = c >> 3;
        int j  = c & 7;
        int ch = j ^ (r & 7);
        gB[p]   = &woT[(size_t)(n0 + r) * DD + ch * 8];
        ldsB[p] = r * 64 + j * 8;
    }

    f32x4 zero = {0.f, 0.f, 0.f, 0.f};
    f32x4 acc[2][4];
#pragma unroll
    for (int i = 0; i < 2; ++i)
#pragma unroll
        for (int j = 0; j < 4; ++j) acc[i][j] = zero;

#pragma unroll
    for (int p = 0; p < 2; ++p) async_copy16((unsigned short*)As0 + ldsA[p], gA[p]);
#pragma unroll
    for (int p = 0; p < 4; ++p) async_copy16((unsigned short*)Bs0 + ldsB[p], gB[p]);
    __syncthreads();

#pragma unroll
    for (int t = 0; t < NKT; ++t) {
        const int kn = (t + 1) * 64;
        unsigned short (*As)[64] = (t & 1) ? As1 : As0;
        unsigned short (*Bs)[64] = (t & 1) ? Bs1 : Bs0;
        unsigned short (*An)[64] = (t & 1) ? As0 : As1;
        unsigned short (*Bn)[64] = (t & 1) ? Bs0 : Bs1;
        if (t + 1 < NKT) {
#pragma unroll
            for (int p = 0; p < 2; ++p)
                async_copy16((unsigned short*)An + ldsA[p], gA[p] + kn);
#pragma unroll
            for (int p = 0; p < 4; ++p)
                async_copy16((unsigned short*)Bn + ldsB[p], gB[p] + kn);
        }
        bf16x8 af0[2], af1[2], bf0[4], bf1[4];
#pragma unroll
        for (int mt = 0; mt < 2; ++mt) {
            int r = mh * 32 + mt * 16 + l16;
            af0[mt] = *(const bf16x8*)&As[r][((quad    ) ^ swz) * 8];
            af1[mt] = *(const bf16x8*)&As[r][((quad + 4) ^ swz) * 8];
        }
#pragma unroll
        for (int nt = 0; nt < 4; ++nt) {
            int r = nh * 64 + nt * 16 + l16;
            bf0[nt] = *(const bf16x8*)&Bs[r][((quad    ) ^ swz) * 8];
            bf1[nt] = *(const bf16x8*)&Bs[r][((quad + 4) ^ swz) * 8];
        }
#pragma unroll
        for (int mt = 0; mt < 2; ++mt)
#pragma unroll
            for (int nt = 0; nt < 4; ++nt) {
                acc[mt][nt] = mfma16(af0[mt], bf0[nt], acc[mt][nt]);
                acc[mt][nt] = mfma16(af1[mt], bf1[nt], acc[mt][nt]);
            }
        __syncthreads();
    }

#pragma unroll
    for (int nt = 0; nt < 4; ++nt) {
        const int n = n0 + nh * 64 + nt * 16 + l16;
        const float bvv = bo[n];
#pragma unroll
        for (int mt = 0; mt < 2; ++mt) {
            const int mbase = m0 + mh * 32 + mt * 16 + quad * 4;
#pragma unroll
            for (int r = 0; r < 4; ++r)
                out[(size_t)(mbase + r) * DD + n] = acc[mt][nt][r] + bvv;
        }
    }
}

// ---------------------------------------------------------------------------
// MFMA flash attention, QBLK=128, XCD swizzle: all 40 chunks of one (b,h)
// co-locate on one XCD -> K/V (1.5 MB per XCD) stay L2-resident.
// ---------------------------------------------------------------------------
__global__ __launch_bounds__(256, 4) void attn_mfma_kernel(
    const unsigned short* __restrict__ Qg, const unsigned short* __restrict__ Kg,
    const unsigned short* __restrict__ Vg, unsigned short* __restrict__ Opart,
    float* __restrict__ Lb)
{
    // XCD decode: 960 blocks; xcd = p%8, 3 bh-groups x 40 chunks per XCD
    const int p0   = blockIdx.x;
    const int xcd  = p0 & 7;
    const int slot = p0 >> 3;               // 0..119
    const int bh_i = (slot / 40) * 8 + xcd; // 0..23
    const int c    = (NCH - 1) - (slot % 40);   // big-qt chunks dispatch first

    int qt, ck, nch;
    if (c < 4)       { qt = c;                            ck = 0;     nch = 1; }
    else if (c < 12) { int t = c - 4;  qt = 4  + (t >> 1); ck = t & 1; nch = 2; }
    else if (c < 24) { int t = c - 12; qt = 8  + t / 3;    ck = t % 3; nch = 3; }
    else             { int t = c - 24; qt = 12 + (t >> 2); ck = t & 3; nch = 4; }
    const int NT   = 2 * qt + 2;
    const int base = NT / nch, rem = NT % nch;
    const int lo   = ck * base + min(ck, rem);
    const int hi   = lo + base + (ck < rem ? 1 : 0);
    const int dlo  = 2 * qt;

    const int tid  = threadIdx.x;
    const int w    = tid >> 6;
    const int lane = tid & 63;
    const int quad = lane >> 4;
    const int l16  = lane & 15;
    const int q0   = qt * 128;

    const size_t bh = (size_t)bh_i;
    const unsigned short* qp = Qg + bh * SS * HDD;
    const unsigned short* kp = Kg + bh * SS * HDD;
    const unsigned short* vp = Vg + bh * HDD * SS;   // [d][s]

    unsigned short* op = Opart + ((size_t)bh * NCH + c) * 128 * HDD;
    float* lp = Lb + ((size_t)bh * NCH + c) * 128;

    __shared__ unsigned short Ks[64][64];        // [key][d], XOR-swizzled chunks
    __shared__ unsigned short Vt[64][64];        // [d][key], XOR-swizzled chunks
    __shared__ unsigned short PsT[4][2][16][72]; // per-wave [qf][query(l16)][key]
    unsigned short* slab = &PsT[w][0][0][0];

    bf16x8 qb0[2], qb1[2];
    int query[2];
#pragma unroll
    for (int qf = 0; qf < 2; ++qf) {
        query[qf] = q0 + w * 32 + qf * 16 + l16;
        qb0[qf] = *(const bf16x8*)&qp[(size_t)query[qf] * HDD + quad * 8];
        qb1[qf] = *(const bf16x8*)&qp[(size_t)query[qf] * HDD + 32 + quad * 8];
    }

    const int pr  = tid >> 3;          // 0..31
    const int po8 = tid & 7;
    const int fs  = l16 & 7;

    i32x4 kpre[2], vpre[2];
#pragma unroll
    for (int p = 0; p < 2; ++p) {
        int r  = pr + p * 32;
        int gc = (po8 ^ (r & 7)) * 8;
        kpre[p] = *(const i32x4*)&kp[(size_t)(lo * 64 + r) * HDD + gc];
        vpre[p] = *(const i32x4*)&vp[(size_t)r * SS + lo * 64 + gc];
    }

    f32x4 zero = {0.f, 0.f, 0.f, 0.f};
    f32x4 o_acc[2][4];
    float l_i[2] = {0.f, 0.f};
#pragma unroll
    for (int qf = 0; qf < 2; ++qf)
#pragma unroll
        for (int i = 0; i < 4; ++i) o_acc[qf][i] = zero;

    for (int kt = lo; kt < hi; ++kt) {
        const int k0 = kt * 64;
        __syncthreads();
#pragma unroll
        for (int p = 0; p < 2; ++p) {
            int r = pr + p * 32;
            *(i32x4*)&Ks[r][po8 * 8] = kpre[p];
            *(i32x4*)&Vt[r][po8 * 8] = vpre[p];
        }
        __syncthreads();

        if (kt + 1 < hi) {
            const int kn = (kt + 1) * 64;
#pragma unroll
            for (int p = 0; p < 2; ++p) {
                int r  = pr + p * 32;
                int gc = (po8 ^ (r & 7)) * 8;
                kpre[p] = *(const i32x4*)&kp[(size_t)(kn + r) * HDD + gc];
                vpre[p] = *(const i32x4*)&vp[(size_t)r * SS + kn + gc];
            }
        }

        // ---- S^T = K·Q^T, softmax, P^T staging ----
        const bool diag = (kt >= dlo);
#pragma unroll
        for (int t = 0; t < 4; ++t) {
            const int row = t * 16 + l16;
            bf16x8 klo = *(const bf16x8*)&Ks[row][((quad    ) ^ fs) * 8];
            bf16x8 khi = *(const bf16x8*)&Ks[row][((quad + 4) ^ fs) * 8];
#pragma unroll
            for (int qf = 0; qf < 2; ++qf) {
                f32x4 s = mfma16(klo, qb0[qf], zero);
                s = mfma16(khi, qb1[qf], s);
                float pv[4];
#pragma unroll
                for (int r = 0; r < 4; ++r) {
                    const int key = k0 + t * 16 + quad * 4 + r;
                    float p = exp2f(s[r]);
                    if (diag && key > query[qf]) p = 0.f;
                    pv[r] = p;
                    l_i[qf] += p;
                }
                uint2 pk;
                pk.x = cvt_pk_bf16(pv[0], pv[1]);
                pk.y = cvt_pk_bf16(pv[2], pv[3]);
                *(uint2*)&slab[(qf * 16 + l16) * 72 + t * 16 + quad * 4] = pk;
            }
        }

        // ---- O^T += V^T · P^T ----
        bf16x8 pb0[2], pb1[2];
#pragma unroll
        for (int qf = 0; qf < 2; ++qf) {
            pb0[qf] = *(const bf16x8*)&slab[(qf * 16 + l16) * 72 + quad * 8];
            pb1[qf] = *(const bf16x8*)&slab[(qf * 16 + l16) * 72 + 32 + quad * 8];
        }
#pragma unroll
        for (int t2 = 0; t2 < 4; ++t2) {
            const int row = t2 * 16 + l16;
            bf16x8 vlo = *(const bf16x8*)&Vt[row][((quad    ) ^ fs) * 8];
            bf16x8 vhi = *(const bf16x8*)&Vt[row][((quad + 4) ^ fs) * 8];
#pragma unroll
            for (int qf = 0; qf < 2; ++qf) {
                o_acc[qf][t2] = mfma16(vlo, pb0[qf], o_acc[qf][t2]);
                o_acc[qf][t2] = mfma16(vhi, pb1[qf], o_acc[qf][t2]);
            }
        }
    }

    // ---- epilogue ----
#pragma unroll
    for (int qf = 0; qf < 2; ++qf) {
        float l = l_i[qf];
        l += __shfl_xor(l, 16);
        l += __shfl_xor(l, 32);
        if (quad == 0) lp[w * 32 + qf * 16 + l16] = l;
#pragma unroll
        for (int t2 = 0; t2 < 4; ++t2) {
            uint2 pk;
            pk.x = cvt_pk_bf16(o_acc[qf][t2][0], o_acc[qf][t2][1]);
            pk.y = cvt_pk_bf16(o_acc[qf][t2][2], o_acc[qf][t2][3]);
            *(uint2*)&slab[(qf * 16 + l16) * 72 + t2 * 16 + quad * 4] = pk;
        }
    }
#pragma unroll
    for (int p2 = 0; p2 < 4; ++p2) {
        int cc  = p2 * 64 + lane;
        int row = cc >> 3, dc = cc & 7;
        *(i32x4*)&op[(size_t)(w * 32 + row) * HDD + dc * 8] =
            *(const i32x4*)&slab[row * 72 + dc * 8];
    }
}

// ---------------------------------------------------------------------------
// Merge the 1..4 chunk partials of each 128-query tile: ctx = sum(O_c)/sum(l_c)
// ---------------------------------------------------------------------------
__global__ __launch_bounds__(256) void merge_kernel(
    const unsigned short* __restrict__ Opart, const float* __restrict__ Lb,
    unsigned short* __restrict__ cb)
{
    const int bx   = blockIdx.x;        // 0..31
    const int qt2  = bx >> 1;
    const int half = bx & 1;
    const int bhn  = blockIdx.y;
    const int b    = bhn / HH, h = bhn % HH;
    const int tid  = threadIdx.x;
    const int row  = tid >> 2;
    const int d0   = (tid & 3) * 16;
    const int rowc = half * 64 + row;
    const int q    = qt2 * 128 + rowc;

    const int nch = (qt2 < 4) ? 1 : (qt2 < 8) ? 2 : (qt2 < 12) ? 3 : 4;
    const int cb0 = (qt2 < 4) ? qt2
                  : (qt2 < 8)  ? (4  + (qt2 - 4)  * 2)
                  : (qt2 < 12) ? (12 + (qt2 - 8)  * 3)
                  :              (24 + (qt2 - 12) * 4);

    float suml = 0.f;
    float accv[16];
#pragma unroll
    for (int i = 0; i < 16; ++i) accv[i] = 0.f;

    for (int ci = 0; ci < nch; ++ci) {
        const size_t base = (size_t)bhn * NCH + cb0 + ci;
        suml += Lb[base * 128 + rowc];
        const unsigned short* o = Opart + (base * 128 + rowc) * HDD + d0;
        i32x4 va = *(const i32x4*)&o[0];
        i32x4 vb = *(const i32x4*)&o[8];
#pragma unroll
        for (int wd = 0; wd < 4; ++wd) {
            unsigned int ua = (unsigned int)va[wd];
            accv[wd * 2 + 0] += __uint_as_float(ua << 16);
            accv[wd * 2 + 1] += __uint_as_float(ua & 0xffff0000u);
            unsigned int ub = (unsigned int)vb[wd];
            accv[8 + wd * 2 + 0] += __uint_as_float(ub << 16);
            accv[8 + wd * 2 + 1] += __uint_as_float(ub & 0xffff0000u);
        }
    }
    const float inv = 1.0f / suml;
    unsigned int res[8];
#pragma unroll
    for (int i = 0; i < 8; ++i)
        res[i] = cvt_pk_bf16(accv[2 * i] * inv, accv[2 * i + 1] * inv);
    unsigned short* dst = &cb[((size_t)(b * SS + q)) * DD + h * HDD + d0];
    *(i32x4*)&dst[0] = *(const i32x4*)&res[0];
    *(i32x4*)&dst[8] = *(const i32x4*)&res[4];
}

// ---------------------------------------------------------------------------
extern "C" void kernel_launch(void* const* d_in, const int* in_sizes, int n_in,
                              void* d_out, int out_size, void* d_ws, size_t ws_size,
                              hipStream_t stream)
{
    const float* x  = (const float*)d_in[0];
    const float* wq = (const float*)d_in[1];
    const float* bq = (const float*)d_in[2];
    const float* wk = (const float*)d_in[3];
    const float* bk = (const float*)d_in[4];
    const float* wv = (const float*)d_in[5];
    const float* bv = (const float*)d_in[6];
    const float* wo = (const float*)d_in[7];
    const float* bo = (const float*)d_in[8];
    float* out = (float*)d_out;

    char* p = (char*)d_ws;
    const size_t XB  = (size_t)BSR * DD * 2;
    const size_t WB  = (size_t)DD * DD * 2;
    const size_t OPB = (size_t)BB * HH * NCH * 128 * HDD * 2;
    const size_t LBB = (size_t)BB * HH * NCH * 128 * 4;
    unsigned short* wqT = (unsigned short*)p;            p += WB;
    unsigned short* wkT = (unsigned short*)p;            p += WB;
    unsigned short* wvT = (unsigned short*)p;            p += WB;
    unsigned short* woT = (unsigned short*)p;            p += WB;
    unsigned short* xb  = (unsigned short*)p;            p += XB;
    unsigned short* Qg  = (unsigned short*)p;            p += XB;
    unsigned short* Kg  = (unsigned short*)p;            p += XB;
    unsigned short* Vg  = (unsigned short*)p;            p += XB;
    unsigned short* cb  = (unsigned short*)p;            p += XB;
    unsigned short* Opart = (unsigned short*)p;          p += OPB;
    float* Lb = (float*)p;                               p += LBB;

    conv_all_kernel<<<dim3(NXB + 576), 256, 0, stream>>>(
        x, wq, wk, wv, wo, xb, wqT, wkT, wvT, woT);
    qkv_gemm_kernel<<<dim3(1152), 256, 0, stream>>>(
        xb, wqT, wkT, wvT, bq, bk, bv, Qg, Kg, Vg);
    attn_mfma_kernel<<<dim3(960), 256, 0, stream>>>(
        Qg, Kg, Vg, Opart, Lb);
    merge_kernel<<<dim3(32, BB * HH), 256, 0, stream>>>(Opart, Lb, cb);
    out_gemm_kernel<<<dim3(384), 256, 0, stream>>>(cb, woT, bo, out);
}